// Round 1
// baseline (292.259 us; speedup 1.0000x reference)
//
#include <hip/hip_runtime.h>

// Involution: out[b, g*64+c, ho, wo] = sum_{kh,kw} xp[b, g*64+c, ho+kh, wo+kw] * W[b,g,kh,kw,ho,wo]
// B=8, C=512, G=8, cpg=64, H=W=Ho=Wo=64, K=7, PAD=3, stride=1, dilation=1. fp32.
//
// Strategy: weights for a pixel are shared across all 64 channels of the group
// -> each thread owns 2 horizontal outputs of one row, holds 49 float2 weights
// in registers for the whole channel loop. x staged per-channel in LDS
// (14 rows x 70 cols of the padded plane), window read as aligned float2.

#define BB 8
#define CC 512
#define GG 8
#define CPG 64
#define HH 64
#define WW 64
#define KK 7
#define PAD 3

#define TILE_ROWS 8              // output rows per block
#define LDS_ROWS (TILE_ROWS + KK - 1)   // 14
#define LDS_COLS (WW + KK - 1)          // 70
#define LDS_ELEMS (LDS_ROWS * LDS_COLS) // 980

__global__ __launch_bounds__(256, 2)
void involution_kernel(const float* __restrict__ x,
                       const float* __restrict__ weight,
                       float* __restrict__ out) {
    const int tid = threadIdx.x;
    const int tx = tid & 31;          // 0..31 -> wo0 = 2*tx
    const int ty = tid >> 5;          // 0..7  -> row within tile
    const int tile = blockIdx.x;      // 0..7 row tile
    const int g = blockIdx.y;         // 0..7
    const int b = blockIdx.z;         // 0..7

    const int wo0 = tx << 1;          // even
    const int hbase = tile * TILE_ROWS;
    const int ho = hbase + ty;

    __shared__ float xs[LDS_ELEMS];

    // ---- preload the 49 per-pixel weights as float2 (covers wo0, wo0+1) ----
    const float* wp = weight + ((b * GG + g) * (KK * KK)) * (HH * WW)
                             + ho * WW + wo0;
    float2 w[KK * KK];
#pragma unroll
    for (int t = 0; t < KK * KK; ++t) {
        w[t] = *(const float2*)(wp + t * (HH * WW));
    }

    const float* xg = x + ((b * CC + g * CPG) * (HH * WW));
    float* og = out + ((b * CC + g * CPG) * (HH * WW)) + ho * WW + wo0;

    for (int c = 0; c < CPG; ++c) {
        // ---- stage padded x plane rows [hbase-3 .. hbase+10], cols [-3..66] ----
        const float* xc = xg + c * (HH * WW);
#pragma unroll
        for (int i = tid; i < LDS_ELEMS; i += 256) {
            const int r = i / LDS_COLS;          // const divisor -> magic mul
            const int s = i - r * LDS_COLS;
            const int xr = hbase + r - PAD;
            const int xcol = s - PAD;
            float v = 0.0f;
            if (xr >= 0 && xr < HH && xcol >= 0 && xcol < WW)
                v = xc[xr * WW + xcol];
            xs[i] = v;
        }
        __syncthreads();

        // ---- compute 2 outputs ----
        float acc0 = 0.0f, acc1 = 0.0f;
#pragma unroll
        for (int kh = 0; kh < KK; ++kh) {
            const float* row = &xs[(ty + kh) * LDS_COLS + wo0];
            const float2 p0 = *(const float2*)(row + 0);
            const float2 p1 = *(const float2*)(row + 2);
            const float2 p2 = *(const float2*)(row + 4);
            const float2 p3 = *(const float2*)(row + 6);
            const float f0 = p0.x, f1 = p0.y, f2 = p1.x, f3 = p1.y;
            const float f4 = p2.x, f5 = p2.y, f6 = p3.x, f7 = p3.y;
            const float2 w0 = w[kh * KK + 0];
            const float2 w1 = w[kh * KK + 1];
            const float2 w2 = w[kh * KK + 2];
            const float2 w3 = w[kh * KK + 3];
            const float2 w4 = w[kh * KK + 4];
            const float2 w5 = w[kh * KK + 5];
            const float2 w6 = w[kh * KK + 6];
            acc0 = fmaf(f0, w0.x, acc0);  acc1 = fmaf(f1, w0.y, acc1);
            acc0 = fmaf(f1, w1.x, acc0);  acc1 = fmaf(f2, w1.y, acc1);
            acc0 = fmaf(f2, w2.x, acc0);  acc1 = fmaf(f3, w2.y, acc1);
            acc0 = fmaf(f3, w3.x, acc0);  acc1 = fmaf(f4, w3.y, acc1);
            acc0 = fmaf(f4, w4.x, acc0);  acc1 = fmaf(f5, w4.y, acc1);
            acc0 = fmaf(f5, w5.x, acc0);  acc1 = fmaf(f6, w5.y, acc1);
            acc0 = fmaf(f6, w6.x, acc0);  acc1 = fmaf(f7, w6.y, acc1);
        }

        float2 o; o.x = acc0; o.y = acc1;
        *(float2*)(og + c * (HH * WW)) = o;

        __syncthreads();   // protect xs before next channel's staging
    }
}

extern "C" void kernel_launch(void* const* d_in, const int* in_sizes, int n_in,
                              void* d_out, int out_size, void* d_ws, size_t ws_size,
                              hipStream_t stream) {
    const float* x = (const float*)d_in[0];
    const float* w = (const float*)d_in[1];
    float* out = (float*)d_out;

    dim3 grid(HH / TILE_ROWS, GG, BB);   // (8, 8, 8)
    dim3 block(256);
    involution_kernel<<<grid, block, 0, stream>>>(x, w, out);
}